// Round 5
// baseline (199.986 us; speedup 1.0000x reference)
//
#include <hip/hip_runtime.h>

#define B_    32
#define S_    64
#define D_    8
#define NE_   512        // S_*D_
#define E_    150000
#define CAP   448        // edges per bin (mean 293, ~9 sigma headroom)
#define NB    4          // bins per block
#define GRID  (NE_ / NB) // 128 blocks; inc (2.4MB) is L2-resident per XCD
#define BLK   1024       // 16 waves: one 32-edge tile per wave covers CAP=448

typedef __attribute__((ext_vector_type(8)))  short  short8;   // 8 bf16
typedef __attribute__((ext_vector_type(16))) float  float16;  // MFMA C/D

__device__ __forceinline__ unsigned short f2bf(float f) {
    union { float f; unsigned int u; } cv; cv.f = f;
    unsigned int u = cv.u;
    return (unsigned short)((u + 0x7fffu + ((u >> 16) & 1u)) >> 16);
}
__device__ __forceinline__ unsigned int pack2bf(float a, float b) {
    return (unsigned int)f2bf(a) | ((unsigned int)f2bf(b) << 16);
}
__device__ __forceinline__ short8 load_pack16(const float* p) {
    float4 u0 = ((const float4*)p)[0], u1 = ((const float4*)p)[1];
    unsigned int pk[4] = { pack2bf(u0.x,u0.y), pack2bf(u0.z,u0.w),
                           pack2bf(u1.x,u1.y), pack2bf(u1.z,u1.w) };
    return *(short8*)pk;
}

// ---------------- single fused kernel, no workspace, no global atomics --------
// Block bid owns bins [bid*NB, bid*NB+NB). It scans ALL edges (L2-resident),
// bins its own into LDS, then runs the MFMA pipeline per bin.
// Layer0 (transposed): H^T = Wa(32x16) . X^T(16xn); Layer1: 2 chained K=16 MFMAs.
// C/D layout: col = lane&31, row = (reg&3) + 8*(reg>>2) + 4*(lane>>5)
// C->B-frag reshuffle in registers via v_permlane32_swap_b32.

#define TILE_COMPUTE(bb, bXv, pvv, vldv)                                        \
  {                                                                             \
    float16 c0;                                                                 \
    _Pragma("unroll")                                                           \
    for (int r = 0; r < 16; ++r)                                                \
        c0[r] = bias0s[bb][(r & 3) + 8 * (r >> 2) + 4 * q];                     \
    c0 = __builtin_amdgcn_mfma_f32_32x32x16_bf16(aWa[bb], (bXv), c0, 0, 0, 0);  \
    unsigned Pw[8];                                                             \
    _Pragma("unroll")                                                           \
    for (int j = 0; j < 8; ++j)                                                 \
        Pw[j] = pack2bf(fmaxf(c0[2 * j], 0.f), fmaxf(c0[2 * j + 1], 0.f));      \
    asm("v_permlane32_swap_b32 %0, %1" : "+v"(Pw[0]), "+v"(Pw[2]));             \
    asm("v_permlane32_swap_b32 %0, %1" : "+v"(Pw[1]), "+v"(Pw[3]));             \
    asm("v_permlane32_swap_b32 %0, %1" : "+v"(Pw[4]), "+v"(Pw[6]));             \
    asm("v_permlane32_swap_b32 %0, %1" : "+v"(Pw[5]), "+v"(Pw[7]));             \
    union { unsigned u[4]; short8 s; } H0c, H1c;                                \
    H0c.u[0] = Pw[0]; H0c.u[1] = Pw[1]; H0c.u[2] = Pw[2]; H0c.u[3] = Pw[3];     \
    H1c.u[0] = Pw[4]; H1c.u[1] = Pw[5]; H1c.u[2] = Pw[6]; H1c.u[3] = Pw[7];     \
    float16 c1;                                                                 \
    _Pragma("unroll")                                                           \
    for (int r = 0; r < 16; ++r)                                                \
        c1[r] = bias1s[bb][(r & 3) + 8 * (r >> 2) + 4 * q];                     \
    c1 = __builtin_amdgcn_mfma_f32_32x32x16_bf16(aWb0[bb], H0c.s, c1, 0, 0, 0); \
    c1 = __builtin_amdgcn_mfma_f32_32x32x16_bf16(aWb1[bb], H1c.s, c1, 0, 0, 0); \
    if (vldv) {                                                                 \
        const int b_e = ((pvv) >> 16) & 31;                                     \
        _Pragma("unroll")                                                       \
        for (int r = 0; r < 16; ++r)                                            \
            atomicAdd(&acc[bb][b_e][(r & 3) + 8 * (r >> 2) + 4 * q],            \
                      fmaxf(c1[r], 0.f));                                       \
        if (q == 0) atomicAdd(&cnts[bb][b_e], 1.f);                             \
    }                                                                           \
  }

__global__ __launch_bounds__(BLK)
void fused_all(const float* __restrict__ nf,
               const float* __restrict__ iw0, const float* __restrict__ ib0,
               const float* __restrict__ iw1, const float* __restrict__ ib1,
               const float* __restrict__ ow0, const float* __restrict__ ob0,
               const float* __restrict__ ow1, const float* __restrict__ ob1,
               const int* __restrict__ inc,
               float* __restrict__ out) {
    const int bid  = blockIdx.x;
    const int tid  = threadIdx.x;
    const int lane = tid & 63;
    const int wav  = tid >> 6;            // 0..15
    const int e32  = lane & 31;
    const int q    = lane >> 5;
    const int base = bid * NB;            // first eidx owned by this block

    __shared__ int   lcount[NB];
    __shared__ int   elist[NB][CAP];      // 7.2 KB
    __shared__ float acc[NB][32][33];     // 16.9 KB
    __shared__ float cnts[NB][32];
    __shared__ float hb[32][33];
    __shared__ float q0t[NB][32 * 33];    // 16.9 KB  [k][o] transposed
    __shared__ float q1t[NB][32 * 17];    // 8.7 KB
    __shared__ float qb0s[NB][32], qb1s[NB][16];
    __shared__ float bias0s[NB][32], bias1s[NB][32];

    if (tid < NB) lcount[tid] = 0;

    // --- A-frags for all NB bins: issued first, latency hides under the scan ---
    short8 aWa[NB], aWb0[NB], aWb1[NB];
    #pragma unroll
    for (int b = 0; b < NB; ++b) {
        const int eidx = base + b;
        aWa[b]  = load_pack16(iw0 + (size_t)eidx * 512  + e32 * 16 + q * 8);
        aWb0[b] = load_pack16(iw1 + (size_t)eidx * 1024 + e32 * 32 + q * 8);
        aWb1[b] = load_pack16(iw1 + (size_t)eidx * 1024 + e32 * 32 + 16 + q * 8);
    }

    // --- LDS staging for all NB bins (independent of the scan) ---
    #pragma unroll
    for (int i0 = 0; i0 < 4; ++i0) {                  // q0t: 4096 entries
        const int i = i0 * BLK + tid;
        const int b = i >> 10, idx = i & 1023;
        const int o = idx >> 5, k = idx & 31;
        q0t[b][k * 33 + o] = ow0[(size_t)(base + b) * 1024 + idx];
    }
    #pragma unroll
    for (int i0 = 0; i0 < 2; ++i0) {                  // q1t: 2048 entries
        const int i = i0 * BLK + tid;
        const int b = i >> 9, idx = i & 511;
        const int o = idx >> 5, k = idx & 31;
        q1t[b][k * 17 + o] = ow1[(size_t)(base + b) * 512 + idx];
    }
    if (tid < 128)      { bias0s[tid >> 5][tid & 31] = ib0[(base + (tid >> 5)) * 32 + (tid & 31)]; }
    else if (tid < 256) { const int t = tid - 128; bias1s[t >> 5][t & 31] = ib1[(base + (t >> 5)) * 32 + (t & 31)]; }
    else if (tid < 384) { const int t = tid - 256; qb0s[t >> 5][t & 31] = ob0[(base + (t >> 5)) * 32 + (t & 31)]; }
    else if (tid < 448) { const int t = tid - 384; qb1s[t >> 4][t & 15] = ob1[(base + (t >> 4)) * 16 + (t & 15)]; }
    else if (tid < 576) { const int t = tid - 448; ((float*)cnts)[t] = 0.f; }
    for (int i = tid; i < NB * 32 * 33; i += BLK) ((float*)acc)[i] = 0.f;
    __syncthreads();

    // --- scan ALL edges; keep the ~NB/NE_ fraction belonging to this block ---
    const int4* inc4 = (const int4*)inc;
    #pragma unroll 2
    for (int i = tid; i < E_; i += BLK) {
        const int4 c = inc4[i];                       // coalesced, L2-resident
        const int lb = c.z * D_ + c.w - base;
        if ((unsigned)lb < NB) {
            const int slot = atomicAdd(&lcount[lb], 1);   // LDS atomic only
            if (slot < CAP) elist[lb][slot] = (c.x << 16) | (c.y * S_ + c.z);
        }
    }
    __syncthreads();

    // --- per-bin bookkeeping + ALL gathers issued upfront (max MLP) ---
    int n_[NB], nt_[NB], pv_[NB]; bool v_[NB]; short8 bX_[NB];
    const int s = (wav << 5) + e32;                   // wave wav owns tile wav
    #pragma unroll
    for (int b = 0; b < NB; ++b) {
        n_[b]  = min(lcount[b], CAP);
        nt_[b] = (n_[b] + 31) >> 5;                   // <= 14 <= 16 waves
        v_[b]  = s < n_[b];
        const int cs = n_[b] > 0 ? min(s, n_[b] - 1) : 0;
        pv_[b] = elist[b][cs];                        // row is 16-bit: nf-safe
    }
    #pragma unroll
    for (int b = 0; b < NB; ++b)
        bX_[b] = load_pack16(nf + (size_t)(pv_[b] & 0xFFFF) * 16 + q * 8);

    // --- MFMA for all bins (wave-uniform guards) ---
    #pragma unroll
    for (int b = 0; b < NB; ++b) {
        if (wav < nt_[b]) {
            TILE_COMPUTE(b, bX_[b], pv_[b], v_[b]);
        }
    }
    __syncthreads();

    // --- epilogue: mean + out0 + out1, per bin; hb reuse is in-wave ordered ---
    if (tid < 512) {
        const int b2 = tid >> 4;                      // batch 0..31
        const int j  = tid & 15;
        #pragma unroll
        for (int b = 0; b < NB; ++b) {
            const float cv  = cnts[b][b2];
            const float inv = cv > 0.f ? 1.0f / cv : 0.0f;
            #pragma unroll
            for (int ss = 0; ss < 2; ++ss) {
                const int oo = j * 2 + ss;
                float d = 0.f;
                #pragma unroll
                for (int k = 0; k < 32; ++k)
                    d = fmaf(q0t[b][k * 33 + oo], acc[b][b2][k], d);
                hb[b2][oo] = fmaxf(fmaf(d, inv, qb0s[b][oo]), 0.f);
            }
            // 16 threads covering b2 are in one wave: LDS same-wave ordering
            float d1 = qb1s[b][j];
            #pragma unroll
            for (int k = 0; k < 32; ++k)
                d1 = fmaf(q1t[b][k * 17 + j], hb[b2][k], d1);
            out[((size_t)b2 * NE_ + (base + b)) * 16 + j] = fmaxf(d1, 0.f);
        }
    }
}

extern "C" void kernel_launch(void* const* d_in, const int* in_sizes, int n_in,
                              void* d_out, int out_size, void* d_ws, size_t ws_size,
                              hipStream_t stream) {
    const float* nf  = (const float*)d_in[0];
    const float* iw0 = (const float*)d_in[1];
    const float* ib0 = (const float*)d_in[2];
    const float* iw1 = (const float*)d_in[3];
    const float* ib1 = (const float*)d_in[4];
    const float* ow0 = (const float*)d_in[5];
    const float* ob0 = (const float*)d_in[6];
    const float* ow1 = (const float*)d_in[7];
    const float* ob1 = (const float*)d_in[8];
    const int*   inc = (const int*)d_in[9];

    (void)d_ws; (void)ws_size;   // workspace intentionally unused

    fused_all<<<GRID, BLK, 0, stream>>>(nf, iw0, ib0, iw1, ib1, ow0, ob0, ow1, ob1,
                                        inc, (float*)d_out);
}

// Round 6
// 124.625 us; speedup vs baseline: 1.6047x; 1.6047x over previous
//
#include <hip/hip_runtime.h>

#define B_    32
#define S_    64
#define D_    8
#define NE_   512        // S_*D_
#define E_    150000
#define CAP   448        // compacted edges per bin (mean 293, ~9 sigma headroom)

// scatter: 37 blocks x 1024 threads x 4 edges = 151552 slots >= E_
#define SC_BLK   1024
#define SC_EPT   4
#define SC_EPB   (SC_BLK * SC_EPT)                 // 4096
#define SC_GRID  ((E_ + SC_EPB - 1) / SC_EPB)      // 37

#define GC_PITCH 32     // ints per bin counter: one 128B line per bin

typedef __attribute__((ext_vector_type(8)))  short  short8;   // 8 bf16 (4 VGPR)
typedef __attribute__((ext_vector_type(16))) float  float16;  // MFMA C/D (16 regs)

__device__ __forceinline__ unsigned short f2bf(float f) {
    union { float f; unsigned int u; } cv; cv.f = f;
    unsigned int u = cv.u;
    return (unsigned short)((u + 0x7fffu + ((u >> 16) & 1u)) >> 16);
}
__device__ __forceinline__ unsigned int pack2bf(float a, float b) {
    return (unsigned int)f2bf(a) | ((unsigned int)f2bf(b) << 16);
}

// ---------------- warm-up: stream every input line into LLC -------------------
// One dword per 64B cache line, ~8 independent guarded loads per thread,
// 65536 threads -> ~450K concurrent line fills (fill-like MLP). Zero stores;
// asm sinks keep the loads alive (guide rule #17).
__global__ __launch_bounds__(256)
void warm_llc(const float* __restrict__ nf,   // 1048576 f -> 65536 lines
              const float* __restrict__ iw0,  //  262144 f -> 16384 lines
              const float* __restrict__ iw1,  //  524288 f -> 32768 lines
              const float* __restrict__ ow0,  //  524288 f -> 32768 lines
              const float* __restrict__ ow1,  //  262144 f -> 16384 lines
              const int*   __restrict__ inc,  //  600000 i -> 37500 lines
              const float* __restrict__ ib0, const float* __restrict__ ib1,
              const float* __restrict__ ob0, const float* __restrict__ ob1) {
    const int t = blockIdx.x * 256 + threadIdx.x;   // 0..65535
    float s0 = 0.f, s1 = 0.f, s2 = 0.f, s3 = 0.f;
    int   si = 0;
    s0 = nf[t * 16];                                  // t < 65536 always
    if (t < 16384) s1 = iw0[t * 16];
    if (t < 32768) s2 = iw1[t * 16];
    if (t < 32768) s3 = ow0[t * 16];
    float s4 = 0.f;
    if (t < 16384) s4 = ow1[t * 16];
    if (t < 37500) si = inc[t * 16];
    float s5 = 0.f;
    if (t < 1024)  s5 = ib0[t * 16] + ib1[t * 16] + ob0[t * 16];
    if (t < 512)   s5 += ob1[t * 16];
    asm volatile("" :: "v"(s0), "v"(s1), "v"(s2), "v"(s3), "v"(s4), "v"(s5), "v"(si));
}

// ---------------- CSR scatter: block-aggregated, line-padded global atomics ----
__global__ __launch_bounds__(SC_BLK)
void scatter_csr(const int* __restrict__ inc,
                 int* __restrict__ gcnt,        // [NE_ * GC_PITCH], zeroed
                 int* __restrict__ payload) {   // [NE_][CAP]
    __shared__ int lcount[NE_];
    __shared__ int lbase[NE_];
    const int tid = threadIdx.x;

    if (tid < NE_) lcount[tid] = 0;
    __syncthreads();

    int ei[SC_EPT], lp[SC_EPT], pl[SC_EPT];
    #pragma unroll
    for (int i = 0; i < SC_EPT; ++i) {
        const int e = blockIdx.x * SC_EPB + i * SC_BLK + tid;   // coalesced
        ei[i] = -1;
        if (e < E_) {
            const int4 c = ((const int4*)inc)[e];   // c0=batch c1=node c2 c3
            ei[i] = c.z * D_ + c.w;
            pl[i] = (c.x << 16) | (c.y * S_ + c.z);
            lp[i] = atomicAdd(&lcount[ei[i]], 1);   // LDS atomic only
        }
    }
    __syncthreads();

    if (tid < NE_) {
        const int c = lcount[tid];
        lbase[tid] = c ? atomicAdd(&gcnt[tid * GC_PITCH], c) : 0;
    }
    __syncthreads();

    #pragma unroll
    for (int i = 0; i < SC_EPT; ++i) {
        if (ei[i] >= 0) {
            const int s = lbase[ei[i]] + lp[i];
            if (s < CAP) payload[ei[i] * CAP + s] = pl[i];
        }
    }
}

// ---------------- MFMA main kernel (round-3 proven version) -------------------
// Layer0 (transposed): H^T = Wa(32x16) . X^T(16xn); Layer1: 2 chained K=16 MFMAs.
// C/D layout: col = lane&31, row = (reg&3) + 8*(reg>>2) + 4*(lane>>5)
// C->B-frag reshuffle in registers via v_permlane32_swap_b32.

#define TILE_COMPUTE(bXv, pvv, vldv)                                            \
  {                                                                             \
    float16 c0;                                                                 \
    _Pragma("unroll")                                                           \
    for (int r = 0; r < 16; ++r)                                                \
        c0[r] = bias0s[(r & 3) + 8 * (r >> 2) + 4 * q];                         \
    c0 = __builtin_amdgcn_mfma_f32_32x32x16_bf16(aWa, (bXv), c0, 0, 0, 0);      \
    unsigned Pw[8];                                                             \
    _Pragma("unroll")                                                           \
    for (int j = 0; j < 8; ++j)                                                 \
        Pw[j] = pack2bf(fmaxf(c0[2 * j], 0.f), fmaxf(c0[2 * j + 1], 0.f));      \
    asm("v_permlane32_swap_b32 %0, %1" : "+v"(Pw[0]), "+v"(Pw[2]));             \
    asm("v_permlane32_swap_b32 %0, %1" : "+v"(Pw[1]), "+v"(Pw[3]));             \
    asm("v_permlane32_swap_b32 %0, %1" : "+v"(Pw[4]), "+v"(Pw[6]));             \
    asm("v_permlane32_swap_b32 %0, %1" : "+v"(Pw[5]), "+v"(Pw[7]));             \
    union { unsigned u[4]; short8 s; } H0c, H1c;                                \
    H0c.u[0] = Pw[0]; H0c.u[1] = Pw[1]; H0c.u[2] = Pw[2]; H0c.u[3] = Pw[3];     \
    H1c.u[0] = Pw[4]; H1c.u[1] = Pw[5]; H1c.u[2] = Pw[6]; H1c.u[3] = Pw[7];     \
    float16 c1;                                                                 \
    _Pragma("unroll")                                                           \
    for (int r = 0; r < 16; ++r)                                                \
        c1[r] = bias1s[(r & 3) + 8 * (r >> 2) + 4 * q];                         \
    c1 = __builtin_amdgcn_mfma_f32_32x32x16_bf16(aWb0, H0c.s, c1, 0, 0, 0);     \
    c1 = __builtin_amdgcn_mfma_f32_32x32x16_bf16(aWb1, H1c.s, c1, 0, 0, 0);     \
    if (vldv) {                                                                 \
        const int b_e = ((pvv) >> 16) & 31;                                     \
        _Pragma("unroll")                                                       \
        for (int r = 0; r < 16; ++r)                                            \
            atomicAdd(&acc[b_e][(r & 3) + 8 * (r >> 2) + 4 * q],                \
                      fmaxf(c1[r], 0.f));                                       \
        if (q == 0) atomicAdd(&cnts[b_e], 1.f);                                 \
    }                                                                           \
  }

__global__ __launch_bounds__(512, 4)
void main_mfma(const float* __restrict__ nf,
               const float* __restrict__ iw0, const float* __restrict__ ib0,
               const float* __restrict__ iw1, const float* __restrict__ ib1,
               const float* __restrict__ ow0, const float* __restrict__ ob0,
               const float* __restrict__ ow1, const float* __restrict__ ob1,
               const int* __restrict__ gcnt, const int* __restrict__ payload,
               float* __restrict__ out) {
    const int bid  = blockIdx.x;          // == eidx (bin)
    const int tid  = threadIdx.x;
    const int lane = tid & 63;
    const int wav  = tid >> 6;            // 0..7
    const int e32  = lane & 31;           // edge-in-tile / A-row
    const int q    = lane >> 5;           // k-half selector

    __shared__ float acc[32][33];
    __shared__ float hb[32][33];
    __shared__ float cnts[32];
    __shared__ float q0t[32 * 33];        // [k][o] transposed, pad 33
    __shared__ float q1t[32 * 17];        // [k][o] transposed, pad 17
    __shared__ float qb0s[32], qb1s[16];
    __shared__ float bias0s[32], bias1s[32];

    // --- issue ALL independent global loads first (max MLP, 2-deep chain max) ---
    const int n = min(gcnt[bid * GC_PITCH], CAP);           // independent load

    const int s0 = (wav << 5) + e32;                        // < 256
    const int s1 = s0 + 256;                                // < 512 (masked later)
    const int pv0 = payload[bid * CAP + s0];                // unconditional
    const int pv1 = payload[bid * CAP + s1];                // unconditional

    short8 aWa, aWb0, aWb1;
    {
        const float* wa = iw0 + (size_t)bid * 512 + e32 * 16 + q * 8;
        float4 u0 = ((const float4*)wa)[0], u1 = ((const float4*)wa)[1];
        unsigned int p[4] = { pack2bf(u0.x,u0.y), pack2bf(u0.z,u0.w),
                              pack2bf(u1.x,u1.y), pack2bf(u1.z,u1.w) };
        aWa = *(short8*)p;
    }
    {
        const float* wb = iw1 + (size_t)bid * 1024 + e32 * 32 + q * 8;
        float4 u0 = ((const float4*)wb)[0], u1 = ((const float4*)wb)[1];
        unsigned int p[4] = { pack2bf(u0.x,u0.y), pack2bf(u0.z,u0.w),
                              pack2bf(u1.x,u1.y), pack2bf(u1.z,u1.w) };
        aWb0 = *(short8*)p;
        const float* wb2 = wb + 16;
        float4 u2 = ((const float4*)wb2)[0], u3 = ((const float4*)wb2)[1];
        unsigned int p2[4] = { pack2bf(u2.x,u2.y), pack2bf(u2.z,u2.w),
                               pack2bf(u3.x,u3.y), pack2bf(u3.z,u3.w) };
        aWb1 = *(short8*)p2;
    }

    // --- gathers: depend only on payload (chain depth 2) ---
    const bool v0 = s0 < n;
    const bool v1 = s1 < n;
    short8 bX0, bX1;
    {
        const float4* xp = (const float4*)(nf + (size_t)(pv0 & 0xFFFF) * 16 + q * 8);
        float4 u0 = xp[0], u1 = xp[1];
        unsigned int pk[4] = { pack2bf(u0.x,u0.y), pack2bf(u0.z,u0.w),
                               pack2bf(u1.x,u1.y), pack2bf(u1.z,u1.w) };
        bX0 = *(short8*)pk;
    }
    {
        const float4* xp = (const float4*)(nf + (size_t)(pv1 & 0xFFFF) * 16 + q * 8);
        float4 u0 = xp[0], u1 = xp[1];
        unsigned int pk[4] = { pack2bf(u0.x,u0.y), pack2bf(u0.z,u0.w),
                               pack2bf(u1.x,u1.y), pack2bf(u1.z,u1.w) };
        bX1 = *(short8*)pk;
    }

    // --- LDS staging (out-weights transposed, biases, acc zero) ---
    for (int i = tid; i < 1024; i += 512) {
        const int o = i >> 5, k = i & 31;
        q0t[k * 33 + o] = ow0[(size_t)bid * 1024 + i];
    }
    { const int o = tid >> 5, k = tid & 31;
      q1t[k * 17 + o] = ow1[(size_t)bid * 512 + tid]; }
    if (tid < 32)       { bias0s[tid] = ib0[bid * 32 + tid]; cnts[tid] = 0.f; }
    else if (tid < 64)  bias1s[tid - 32] = ib1[bid * 32 + (tid - 32)];
    else if (tid < 96)  qb0s[tid - 64] = ob0[bid * 32 + (tid - 64)];
    else if (tid < 112) qb1s[tid - 96] = ob1[bid * 16 + (tid - 96)];
    for (int i = tid; i < 32 * 33; i += 512) ((float*)acc)[i] = 0.f;
    __syncthreads();

    // --- both tiles, straight-line ---
    TILE_COMPUTE(bX0, pv0, v0);
    TILE_COMPUTE(bX1, pv1, v1);
    __syncthreads();

    // --- mean + out layer 0: thread -> (b = tid>>4, outputs 2*(tid&15)..) ---
    {
        const int b  = tid >> 4;
        const int j  = tid & 15;
        const float cv  = cnts[b];
        const float inv = cv > 0.f ? 1.0f / cv : 0.0f;
        #pragma unroll
        for (int s = 0; s < 2; ++s) {
            const int oo = j * 2 + s;
            float d = 0.f;
            #pragma unroll
            for (int k = 0; k < 32; ++k) d = fmaf(q0t[k * 33 + oo], acc[b][k], d);
            hb[b][oo] = fmaxf(fmaf(d, inv, qb0s[oo]), 0.f);
        }
    }
    __syncthreads();

    // --- out layer 1: thread -> (b = tid>>4, o = tid&15) ---
    {
        const int b = tid >> 4;
        const int o = tid & 15;
        float d = qb1s[o];
        #pragma unroll
        for (int k = 0; k < 32; ++k) d = fmaf(q1t[k * 17 + o], hb[b][k], d);
        out[((size_t)b * NE_ + bid) * 16 + o] = fmaxf(d, 0.f);
    }
}

extern "C" void kernel_launch(void* const* d_in, const int* in_sizes, int n_in,
                              void* d_out, int out_size, void* d_ws, size_t ws_size,
                              hipStream_t stream) {
    const float* nf  = (const float*)d_in[0];
    const float* iw0 = (const float*)d_in[1];
    const float* ib0 = (const float*)d_in[2];
    const float* iw1 = (const float*)d_in[3];
    const float* ib1 = (const float*)d_in[4];
    const float* ow0 = (const float*)d_in[5];
    const float* ob0 = (const float*)d_in[6];
    const float* ow1 = (const float*)d_in[7];
    const float* ob1 = (const float*)d_in[8];
    const int*   inc = (const int*)d_in[9];

    int* gcnt    = (int*)d_ws;                                   // [NE_*GC_PITCH] 64 KB
    int* payload = (int*)((char*)d_ws + NE_ * GC_PITCH * 4);     // [NE_][CAP]

    warm_llc<<<256, 256, 0, stream>>>(nf, iw0, iw1, ow0, ow1, inc, ib0, ib1, ob0, ob1);
    hipMemsetAsync(gcnt, 0, NE_ * GC_PITCH * sizeof(int), stream);
    scatter_csr<<<SC_GRID, SC_BLK, 0, stream>>>(inc, gcnt, payload);
    main_mfma<<<NE_, 512, 0, stream>>>(nf, iw0, ib0, iw1, ib1, ow0, ob0, ow1, ob1,
                                       gcnt, payload, (float*)d_out);
}

// Round 7
// 119.049 us; speedup vs baseline: 1.6799x; 1.0468x over previous
//
#include <hip/hip_runtime.h>

#define B_    32
#define S_    64
#define D_    8
#define NE_   512        // S_*D_
#define E_    150000
#define CAP   448        // compacted edges per bin (mean 293, ~9 sigma headroom)

// scatter: 37 blocks x 1024 threads x 4 edges = 151552 slots >= E_
#define SC_BLK   1024
#define SC_EPT   4
#define SC_EPB   (SC_BLK * SC_EPT)                 // 4096
#define SC_GRID  ((E_ + SC_EPB - 1) / SC_EPB)      // 37
#define SLOTS    32                                 // per (bin,blk); mean 8, +8.5 sigma
#define PITCH    (SC_GRID * SLOTS)                  // 1184 ints per bin

// ws: cnt2D[NE_][SC_GRID] at 0 (76KB) | payload2D[NE_][PITCH] at 128KB (2.4MB)
#define PAYLOAD_BYTE_OFF 131072

typedef __attribute__((ext_vector_type(8)))  short  short8;   // 8 bf16 (4 VGPR)
typedef __attribute__((ext_vector_type(16))) float  float16;  // MFMA C/D (16 regs)

__device__ __forceinline__ unsigned short f2bf(float f) {
    union { float f; unsigned int u; } cv; cv.f = f;
    unsigned int u = cv.u;
    return (unsigned short)((u + 0x7fffu + ((u >> 16) & 1u)) >> 16);
}
__device__ __forceinline__ unsigned int pack2bf(float a, float b) {
    return (unsigned int)f2bf(a) | ((unsigned int)f2bf(b) << 16);
}

// ---------------- init-free binning scatter (no memset, no global atomics) -----
// cnt2D[bin][blk] is fully overwritten each run -> workspace poison harmless.
__global__ __launch_bounds__(SC_BLK)
void scatter_bin(const int* __restrict__ inc,
                 int* __restrict__ cnt2D,        // [NE_][SC_GRID]
                 int* __restrict__ payload2D) {  // [NE_][PITCH]
    __shared__ int lcount[NE_];
    const int tid = threadIdx.x;

    if (tid < NE_) lcount[tid] = 0;
    __syncthreads();

    int ei[SC_EPT], lp[SC_EPT], pl[SC_EPT];
    #pragma unroll
    for (int i = 0; i < SC_EPT; ++i) {
        const int e = blockIdx.x * SC_EPB + i * SC_BLK + tid;   // coalesced
        ei[i] = -1;
        if (e < E_) {
            const int4 c = ((const int4*)inc)[e];   // c0=batch c1=node c2 c3
            ei[i] = c.z * D_ + c.w;
            pl[i] = (c.x << 16) | (c.y * S_ + c.z);
            lp[i] = atomicAdd(&lcount[ei[i]], 1);   // LDS atomic only
        }
    }
    // deterministic slot -> store immediately, no cross-block dependency
    #pragma unroll
    for (int i = 0; i < SC_EPT; ++i)
        if (ei[i] >= 0 && lp[i] < SLOTS)
            payload2D[ei[i] * PITCH + blockIdx.x * SLOTS + lp[i]] = pl[i];
    __syncthreads();
    if (tid < NE_)
        cnt2D[tid * SC_GRID + blockIdx.x] = min(lcount[tid], SLOTS);
}

// ---------------- MFMA main kernel ----------------
// Layer0 (transposed): H^T = Wa(32x16) . X^T(16xn); Layer1: 2 chained K=16 MFMAs.
// C/D layout: col = lane&31, row = (reg&3) + 8*(reg>>2) + 4*(lane>>5)
// C->B-frag reshuffle in registers via v_permlane32_swap_b32.
// Prologue: single-wave shuffle scan over 37 per-block counts (no Hillis-Steele),
// payload compaction loads prefetched into registers before the first barrier.

#define TILE_COMPUTE(bXv, pvv, vldv)                                            \
  {                                                                             \
    float16 c0;                                                                 \
    _Pragma("unroll")                                                           \
    for (int r = 0; r < 16; ++r)                                                \
        c0[r] = bias0s[(r & 3) + 8 * (r >> 2) + 4 * q];                         \
    c0 = __builtin_amdgcn_mfma_f32_32x32x16_bf16(aWa, (bXv), c0, 0, 0, 0);      \
    unsigned Pw[8];                                                             \
    _Pragma("unroll")                                                           \
    for (int j = 0; j < 8; ++j)                                                 \
        Pw[j] = pack2bf(fmaxf(c0[2 * j], 0.f), fmaxf(c0[2 * j + 1], 0.f));      \
    asm("v_permlane32_swap_b32 %0, %1" : "+v"(Pw[0]), "+v"(Pw[2]));             \
    asm("v_permlane32_swap_b32 %0, %1" : "+v"(Pw[1]), "+v"(Pw[3]));             \
    asm("v_permlane32_swap_b32 %0, %1" : "+v"(Pw[4]), "+v"(Pw[6]));             \
    asm("v_permlane32_swap_b32 %0, %1" : "+v"(Pw[5]), "+v"(Pw[7]));             \
    union { unsigned u[4]; short8 s; } H0c, H1c;                                \
    H0c.u[0] = Pw[0]; H0c.u[1] = Pw[1]; H0c.u[2] = Pw[2]; H0c.u[3] = Pw[3];     \
    H1c.u[0] = Pw[4]; H1c.u[1] = Pw[5]; H1c.u[2] = Pw[6]; H1c.u[3] = Pw[7];     \
    float16 c1;                                                                 \
    _Pragma("unroll")                                                           \
    for (int r = 0; r < 16; ++r)                                                \
        c1[r] = bias1s[(r & 3) + 8 * (r >> 2) + 4 * q];                         \
    c1 = __builtin_amdgcn_mfma_f32_32x32x16_bf16(aWb0, H0c.s, c1, 0, 0, 0);     \
    c1 = __builtin_amdgcn_mfma_f32_32x32x16_bf16(aWb1, H1c.s, c1, 0, 0, 0);     \
    if (vldv) {                                                                 \
        const int b_e = ((pvv) >> 16) & 31;                                     \
        _Pragma("unroll")                                                       \
        for (int r = 0; r < 16; ++r)                                            \
            atomicAdd(&acc[b_e][(r & 3) + 8 * (r >> 2) + 4 * q],                \
                      fmaxf(c1[r], 0.f));                                       \
        if (q == 0) atomicAdd(&cnts[b_e], 1.f);                                 \
    }                                                                           \
  }

__global__ __launch_bounds__(512, 4)
void main_mfma(const float* __restrict__ nf,
               const float* __restrict__ iw0, const float* __restrict__ ib0,
               const float* __restrict__ iw1, const float* __restrict__ ib1,
               const float* __restrict__ ow0, const float* __restrict__ ob0,
               const float* __restrict__ ow1, const float* __restrict__ ob1,
               const int* __restrict__ cnt2D, const int* __restrict__ payload2D,
               float* __restrict__ out) {
    const int bid  = blockIdx.x;          // == eidx (bin)
    const int tid  = threadIdx.x;
    const int wav  = tid >> 6;            // 0..7
    const int lane = tid & 63;
    const int e32  = lane & 31;           // edge-in-tile / A-row
    const int q    = lane >> 5;           // k-half selector

    __shared__ float acc[32][33];
    __shared__ float hb[32][33];
    __shared__ float cnts[32];
    __shared__ float q0t[32 * 33];        // [k][o] transposed, pad 33
    __shared__ float q1t[32 * 17];        // [k][o] transposed, pad 17
    __shared__ float qb0s[32], qb1s[16];
    __shared__ float bias0s[32], bias1s[32];
    __shared__ int   sbase[64], scount[64];
    __shared__ int   sn;
    __shared__ int   elist[512];          // first min(n,CAP) valid; rest masked

    // --- prefetch compaction payloads into registers (issued pre-barrier) ---
    const int* Pb = payload2D + (size_t)bid * PITCH;
    const int p0 = tid, p1 = tid + 512, p2 = tid + 1024;
    const int r0 = Pb[p0];
    const int r1 = Pb[p1];
    const int r2 = (p2 < PITCH) ? Pb[p2] : 0;

    // --- wave 0: load 37 counts, 6-step shuffle inclusive scan ---
    if (tid < 64) {
        int v = (tid < SC_GRID) ? cnt2D[bid * SC_GRID + tid] : 0;
        scount[tid] = v;
        int incl = v;
        #pragma unroll
        for (int off = 1; off < 64; off <<= 1) {
            const int t = __shfl_up(incl, off);
            if (tid >= off) incl += t;
        }
        sbase[tid] = incl - v;            // exclusive base
        if (tid == SC_GRID - 1) sn = min(incl, CAP);
    }

    // --- per-lane A-frags (weights, packed bf16) ---
    short8 aWa, aWb0, aWb1;
    {
        const float* wa = iw0 + (size_t)bid * 512 + e32 * 16 + q * 8;
        float4 u0 = ((const float4*)wa)[0], u1 = ((const float4*)wa)[1];
        unsigned int p[4] = { pack2bf(u0.x,u0.y), pack2bf(u0.z,u0.w),
                              pack2bf(u1.x,u1.y), pack2bf(u1.z,u1.w) };
        aWa = *(short8*)p;
    }
    {
        const float* wb = iw1 + (size_t)bid * 1024 + e32 * 32 + q * 8;
        float4 u0 = ((const float4*)wb)[0], u1 = ((const float4*)wb)[1];
        unsigned int p[4] = { pack2bf(u0.x,u0.y), pack2bf(u0.z,u0.w),
                              pack2bf(u1.x,u1.y), pack2bf(u1.z,u1.w) };
        aWb0 = *(short8*)p;
        const float* wb2 = wb + 16;
        float4 u2 = ((const float4*)wb2)[0], u3 = ((const float4*)wb2)[1];
        unsigned int p2k[4] = { pack2bf(u2.x,u2.y), pack2bf(u2.z,u2.w),
                                pack2bf(u3.x,u3.y), pack2bf(u3.z,u3.w) };
        aWb1 = *(short8*)p2k;
    }

    // --- LDS staging (out-weights transposed, biases, acc zero) ---
    for (int i = tid; i < 1024; i += 512) {
        const int o = i >> 5, k = i & 31;
        q0t[k * 33 + o] = ow0[(size_t)bid * 1024 + i];
    }
    { const int o = tid >> 5, k = tid & 31;
      q1t[k * 17 + o] = ow1[(size_t)bid * 512 + tid]; }
    if (tid < 32)       { bias0s[tid] = ib0[bid * 32 + tid]; cnts[tid] = 0.f; }
    else if (tid < 64)  bias1s[tid - 32] = ib1[bid * 32 + (tid - 32)];
    else if (tid < 96)  qb0s[tid - 64] = ob0[bid * 32 + (tid - 64)];
    else if (tid < 112) qb1s[tid - 96] = ob1[bid * 16 + (tid - 96)];
    for (int i = tid; i < 32 * 33; i += 512) ((float*)acc)[i] = 0.f;
    __syncthreads();

    // --- compaction: registers -> elist (LDS only, no global traffic) ---
    {
        const int blk0 = p0 >> 5, sl0 = p0 & 31;
        if (sl0 < scount[blk0]) {
            const int idx = sbase[blk0] + sl0;
            if (idx < CAP) elist[idx] = r0;
        }
        const int blk1 = p1 >> 5, sl1 = p1 & 31;
        if (sl1 < scount[blk1]) {
            const int idx = sbase[blk1] + sl1;
            if (idx < CAP) elist[idx] = r1;
        }
        if (p2 < PITCH) {
            const int blk2 = p2 >> 5, sl2 = p2 & 31;
            if (sl2 < scount[blk2]) {
                const int idx = sbase[blk2] + sl2;
                if (idx < CAP) elist[idx] = r2;
            }
        }
    }
    __syncthreads();

    // --- both tiles: unconditional reads (garbage masked; row is 16-bit safe) ---
    const int n  = sn;
    const int s0 = (wav << 5) + e32;      // < 256
    const int s1 = s0 + 256;              // < 512
    const int pv0 = elist[s0];
    const int pv1 = elist[s1];
    const bool v0 = s0 < n;
    const bool v1 = s1 < n;

    short8 bX0, bX1;
    {
        const float4* xp = (const float4*)(nf + (size_t)(pv0 & 0xFFFF) * 16 + q * 8);
        float4 u0 = xp[0], u1 = xp[1];
        unsigned int pk[4] = { pack2bf(u0.x,u0.y), pack2bf(u0.z,u0.w),
                               pack2bf(u1.x,u1.y), pack2bf(u1.z,u1.w) };
        bX0 = *(short8*)pk;
    }
    {
        const float4* xp = (const float4*)(nf + (size_t)(pv1 & 0xFFFF) * 16 + q * 8);
        float4 u0 = xp[0], u1 = xp[1];
        unsigned int pk[4] = { pack2bf(u0.x,u0.y), pack2bf(u0.z,u0.w),
                               pack2bf(u1.x,u1.y), pack2bf(u1.z,u1.w) };
        bX1 = *(short8*)pk;
    }

    TILE_COMPUTE(bX0, pv0, v0);
    TILE_COMPUTE(bX1, pv1, v1);
    __syncthreads();

    // --- mean + out layer 0: thread -> (b = tid>>4, outputs 2*(tid&15)..) ---
    {
        const int b  = tid >> 4;
        const int j  = tid & 15;
        const float cv  = cnts[b];
        const float inv = cv > 0.f ? 1.0f / cv : 0.0f;
        #pragma unroll
        for (int s = 0; s < 2; ++s) {
            const int oo = j * 2 + s;
            float d = 0.f;
            #pragma unroll
            for (int k = 0; k < 32; ++k) d = fmaf(q0t[k * 33 + oo], acc[b][k], d);
            hb[b][oo] = fmaxf(fmaf(d, inv, qb0s[oo]), 0.f);
        }
    }
    __syncthreads();

    // --- out layer 1: thread -> (b = tid>>4, o = tid&15) ---
    {
        const int b = tid >> 4;
        const int o = tid & 15;
        float d = qb1s[o];
        #pragma unroll
        for (int k = 0; k < 32; ++k) d = fmaf(q1t[k * 17 + o], hb[b][k], d);
        out[((size_t)b * NE_ + bid) * 16 + o] = fmaxf(d, 0.f);
    }
}

extern "C" void kernel_launch(void* const* d_in, const int* in_sizes, int n_in,
                              void* d_out, int out_size, void* d_ws, size_t ws_size,
                              hipStream_t stream) {
    const float* nf  = (const float*)d_in[0];
    const float* iw0 = (const float*)d_in[1];
    const float* ib0 = (const float*)d_in[2];
    const float* iw1 = (const float*)d_in[3];
    const float* ib1 = (const float*)d_in[4];
    const float* ow0 = (const float*)d_in[5];
    const float* ob0 = (const float*)d_in[6];
    const float* ow1 = (const float*)d_in[7];
    const float* ob1 = (const float*)d_in[8];
    const int*   inc = (const int*)d_in[9];

    int* cnt2D     = (int*)d_ws;
    int* payload2D = (int*)((char*)d_ws + PAYLOAD_BYTE_OFF);

    scatter_bin<<<SC_GRID, SC_BLK, 0, stream>>>(inc, cnt2D, payload2D);
    main_mfma<<<NE_, 512, 0, stream>>>(nf, iw0, ib0, iw1, ib1, ow0, ob0, ow1, ob1,
                                       cnt2D, payload2D, (float*)d_out);
}